// Round 1
// baseline (241.740 us; speedup 1.0000x reference)
//
#include <hip/hip_runtime.h>

// NetVladCNN: B=64, D=512, H=W=32 (N=1024), K=64
// K1: per (b, 4-w-block): features = w @ x  (MFMA bf16), softmax over H, a -> ws (bf16)
// K2: per (b, 64-d-block): V = a @ x^T - 32*c, normalize over K, yw (B,K,D) f32
// K3: transpose (B,K,D) -> (D,K,B)
// XCD swizzle: b = blockIdx & 63 so same-b blocks share one XCD's L2.

typedef __attribute__((ext_vector_type(8))) short short8;
typedef __attribute__((ext_vector_type(8))) unsigned short u16x8;
typedef __attribute__((ext_vector_type(4))) float f32x4;
typedef unsigned short u16;
typedef unsigned int u32;

__device__ __forceinline__ u16 f2bf(float f) {
  union { float f; u32 u; } v; v.f = f;
  u32 u = v.u;
  return (u16)((u + 0x7fffu + ((u >> 16) & 1u)) >> 16);  // RNE
}

// ---------------- Kernel 1: conv + softmax(H) ----------------
// grid 512 = (wb 8)*(b 64), block 256 (4 waves). w0 = wb*4; j = h*4+wl (128 j's).
__global__ __launch_bounds__(256, 2) void k1_conv_softmax(
    const float* __restrict__ x, const float* __restrict__ wgt,
    u16* __restrict__ a_ws)
{
  const int blk = blockIdx.x;
  const int b  = blk & 63;          // XCD = b%8
  const int wb = blk >> 6;
  const int w0 = wb * 4;
  const int tid  = threadIdx.x;
  const int lane = tid & 63;
  const int wv   = tid >> 6;

  __shared__ __align__(16) char smem[64 * 132 * 4];      // 33792 B
  u16  (*as)[40] = (u16 (*)[40])smem;                    // w tile [k][dd]   (5120 B)
  u16  (*bs)[40] = (u16 (*)[40])(smem + 5120);           // x^T tile [j][dd], dd-block ^ (j&3) swizzle (10240 B)
  float (*F)[132] = (float (*)[132])smem;                // epilogue scores

  f32x4 acc[4][2];
#pragma unroll
  for (int mt = 0; mt < 4; mt++)
#pragma unroll
    for (int nt = 0; nt < 2; nt++) acc[mt][nt] = (f32x4){0.f, 0.f, 0.f, 0.f};

  const float* xb = x + (size_t)b * 512 * 1024;
  const int jw0 = wv * 32;
  const int row = lane & 15;
  const int q   = lane >> 4;
  const int ka = tid >> 2, sega = tid & 3;   // A staging
  const int hh = tid >> 4, ddp = tid & 15;   // B staging

  for (int d0 = 0; d0 < 512; d0 += 32) {
    { // A: w[k][d0+dd] -> as[k][dd], 8 contiguous d per thread
      const float* src = wgt + ka * 512 + d0 + sega * 8;
      f32x4 f0 = *(const f32x4*)src;
      f32x4 f1 = *(const f32x4*)(src + 4);
      u16x8 t;
#pragma unroll
      for (int i = 0; i < 4; i++) { t[i] = f2bf(f0[i]); t[4 + i] = f2bf(f1[i]); }
      *(u16x8*)&as[ka][sega * 8] = t;
    }
    // B: x[b][d0+2ddp(+1)][h*32+w0 .. +3] -> bs[j][2ddp], pack 2 d's per b32 write
#pragma unroll
    for (int i = 0; i < 2; i++) {
      const int h = hh * 2 + i;
      const float* px = xb + (size_t)(d0 + 2 * ddp) * 1024 + h * 32 + w0;
      f32x4 g0 = *(const f32x4*)px;
      f32x4 g1 = *(const f32x4*)(px + 1024);
      const int cb = ddp >> 2;
      const int co = (ddp & 3) * 2;
#pragma unroll
      for (int wl = 0; wl < 4; wl++) {
        const int j = h * 4 + wl;
        u32 p = (u32)f2bf(g0[wl]) | ((u32)f2bf(g1[wl]) << 16);
        *(u32*)&bs[j][((cb ^ wl) * 8) + co] = p;
      }
    }
    __syncthreads();
    short8 af[4];
#pragma unroll
    for (int mt = 0; mt < 4; mt++) af[mt] = *(const short8*)&as[mt * 16 + row][q * 8];
#pragma unroll
    for (int nt = 0; nt < 2; nt++) {
      const int j = jw0 + nt * 16 + row;
      short8 bf = *(const short8*)&bs[j][(q ^ (j & 3)) * 8];
#pragma unroll
      for (int mt = 0; mt < 4; mt++)
        acc[mt][nt] = __builtin_amdgcn_mfma_f32_16x16x32_bf16(af[mt], bf, acc[mt][nt], 0, 0, 0);
    }
    __syncthreads();
  }

  // dump C frags (col=lane&15, row=quad*4+reg) to F[k][j]
#pragma unroll
  for (int mt = 0; mt < 4; mt++)
#pragma unroll
    for (int nt = 0; nt < 2; nt++) {
      const int j = jw0 + nt * 16 + row;
#pragma unroll
      for (int r = 0; r < 4; r++)
        F[mt * 16 + q * 4 + r][j] = acc[mt][nt][r];
    }
  __syncthreads();

  { // softmax over h for (k=tid>>2, wl=tid&3); write bf16 a
    const int k = tid >> 2, wl = tid & 3;
    float m = -1e30f;
#pragma unroll
    for (int h = 0; h < 32; h++) m = fmaxf(m, F[k][h * 4 + wl]);
    float s = 0.f;
#pragma unroll
    for (int h = 0; h < 32; h++) {
      float e = __expf(F[k][h * 4 + wl] - m);
      F[k][h * 4 + wl] = e;
      s += e;
    }
    const float inv = 1.0f / s;
    u16* arow = a_ws + ((size_t)b * 64 + k) * 1024 + w0 + wl;
#pragma unroll
    for (int h = 0; h < 32; h++)
      arow[h * 32] = f2bf(F[k][h * 4 + wl] * inv);
  }
}

// ---------------- Kernel 2: V = a@x^T - 32c, normalize over K ----------------
// grid 512 = (db 8)*(b 64), block 256. d0 = db*64.
__global__ __launch_bounds__(256, 2) void k2_aggregate(
    const float* __restrict__ x, const u16* __restrict__ a_ws,
    const float* __restrict__ cc, float* __restrict__ yw)
{
  const int blk = blockIdx.x;
  const int b  = blk & 63;
  const int db = blk >> 6;
  const int d0 = db * 64;
  const int tid  = threadIdx.x;
  const int lane = tid & 63;
  const int wv   = tid >> 6;

  __shared__ __align__(16) char smem[64 * 68 * 4 + 4 * 64 * 4 + 64 * 4];  // 18688 B
  u16  (*as)[40] = (u16 (*)[40])smem;            // a tile [k][nn]
  u16  (*bs)[40] = (u16 (*)[40])(smem + 5120);   // x tile [dl][nn]
  float (*V)[68] = (float (*)[68])smem;          // epilogue
  float* ss = (float*)(smem + 64 * 68 * 4);      // [4][64] partial sumsq
  float* rs = ss + 256;                          // [64] 1/norm

  f32x4 acc[4];
#pragma unroll
  for (int mt = 0; mt < 4; mt++) acc[mt] = (f32x4){0.f, 0.f, 0.f, 0.f};

  const float* xb = x + (size_t)b * 512 * 1024;
  const u16*   ab = a_ws + (size_t)b * 64 * 1024;
  const int row = lane & 15, q = lane >> 4;
  const int kr = tid >> 2, seg = tid & 3;        // kr = k for A, = dl for B

  for (int n0 = 0; n0 < 1024; n0 += 32) {
    *(u16x8*)&as[kr][seg * 8] = *(const u16x8*)(ab + kr * 1024 + n0 + seg * 8);
    {
      const float* px = xb + (size_t)(d0 + kr) * 1024 + n0 + seg * 8;
      f32x4 g0 = *(const f32x4*)px;
      f32x4 g1 = *(const f32x4*)(px + 4);
      u16x8 t;
#pragma unroll
      for (int i = 0; i < 4; i++) { t[i] = f2bf(g0[i]); t[4 + i] = f2bf(g1[i]); }
      *(u16x8*)&bs[kr][seg * 8] = t;
    }
    __syncthreads();
    short8 bf = *(const short8*)&bs[wv * 16 + row][q * 8];
#pragma unroll
    for (int mt = 0; mt < 4; mt++) {
      short8 af = *(const short8*)&as[mt * 16 + row][q * 8];
      acc[mt] = __builtin_amdgcn_mfma_f32_16x16x32_bf16(af, bf, acc[mt], 0, 0, 0);
    }
    __syncthreads();
  }

  { // frags -> V[k][dl], fused -32*c  (Sum_n a = 32 exactly: softmax cols sum to 1)
    const int dl = wv * 16 + row;
#pragma unroll
    for (int mt = 0; mt < 4; mt++)
#pragma unroll
      for (int r = 0; r < 4; r++) {
        const int k = mt * 16 + q * 4 + r;
        V[k][dl] = acc[mt][r] - 32.0f * cc[k * 512 + d0 + dl];
      }
  }
  __syncthreads();
  { // sumsq over k, 4 partials per dl
    const int dl = tid & 63, part = tid >> 6;
    float s = 0.f;
#pragma unroll
    for (int r = 0; r < 16; r++) { const float v = V[part * 16 + r][dl]; s += v * v; }
    ss[part * 64 + dl] = s;
  }
  __syncthreads();
  if (tid < 64) {
    const float t = ss[tid] + ss[64 + tid] + ss[128 + tid] + ss[192 + tid];
    rs[tid] = 1.0f / fmaxf(sqrtf(t), 1e-12f);   // 2nd normalize is identity (||y||=1)
  }
  __syncthreads();
  { // write yw[b][k][d0+dl], lanes along dl -> coalesced
    const int dl = tid & 63, kg = tid >> 6;
    const float r = rs[dl];
    float* dst = yw + (size_t)b * 32768 + d0 + dl;
#pragma unroll
    for (int i = 0; i < 16; i++) {
      const int k = kg * 16 + i;
      dst[(size_t)k * 512] = V[k][dl] * r;
    }
  }
}

// ---------------- Kernel 3: (B,K,D) -> (D,K,B) ----------------
// grid 512 = (dt 8)*(k 64), block 256, 64x64 tile per (k, d-block)
__global__ __launch_bounds__(256) void k3_transpose(
    const float* __restrict__ yw, float* __restrict__ out)
{
  const int blk = blockIdx.x;
  const int k  = blk & 63;
  const int dt = blk >> 6;
  const int d0 = dt * 64;
  const int tid = threadIdx.x;
  __shared__ float T[64][68];
  {
    const int bl = tid >> 2, seg = tid & 3;
    const float* src = yw + (size_t)bl * 32768 + k * 512 + d0 + seg * 16;
#pragma unroll
    for (int i = 0; i < 4; i++) {
      f32x4 v = *(const f32x4*)(src + i * 4);
#pragma unroll
      for (int jj = 0; jj < 4; jj++) T[seg * 16 + i * 4 + jj][bl] = v[jj];
    }
  }
  __syncthreads();
  {
    const int dl = tid >> 2, bseg = tid & 3;
    float* dst = out + (size_t)(d0 + dl) * 4096 + k * 64 + bseg * 16;
    const float* srcT = &T[dl][bseg * 16];
#pragma unroll
    for (int i = 0; i < 4; i++)
      *(f32x4*)(dst + i * 4) = *(const f32x4*)(srcT + i * 4);
  }
}

extern "C" void kernel_launch(void* const* d_in, const int* in_sizes, int n_in,
                              void* d_out, int out_size, void* d_ws, size_t ws_size,
                              hipStream_t stream) {
  const float* x = (const float*)d_in[0];
  const float* w = (const float*)d_in[1];
  const float* c = (const float*)d_in[2];
  float* out = (float*)d_out;
  u16*   a_ws = (u16*)d_ws;                                   // 8 MiB bf16 a (B,K,N)
  float* yw   = (float*)((char*)d_ws + (size_t)8 * 1024 * 1024);  // 8 MiB (B,K,D)
  k1_conv_softmax<<<dim3(512), dim3(256), 0, stream>>>(x, w, a_ws);
  k2_aggregate<<<dim3(512), dim3(256), 0, stream>>>(x, a_ws, c, yw);
  k3_transpose<<<dim3(512), dim3(256), 0, stream>>>(yw, out);
}